// Round 1
// baseline (1751.584 us; speedup 1.0000x reference)
//
#include <hip/hip_runtime.h>
#include <math.h>

// Problem constants (from reference)
#define TT    48
#define BB    96
#define DGv   192
#define DHv   384
#define NSTEP 47      // T-1 scan steps
#define SETI  3       // inner settling iterations
#define NWAVE 6       // 384 threads / 64

__device__ __forceinline__ float wave_reduce(float v) {
#pragma unroll
  for (int off = 32; off; off >>= 1) v += __shfl_xor(v, off, 64);
  return v;
}

// Block-wide sum of N values across 384 threads (6 waves).
// All threads return identical sums. 2 barriers.
template <int N>
__device__ __forceinline__ void block_reduce(float (&v)[N], float* red, int tid) {
  const int lane = tid & 63, wv = tid >> 6;
#pragma unroll
  for (int c = 0; c < N; ++c) {
#pragma unroll
    for (int off = 32; off; off >>= 1) v[c] += __shfl_xor(v[c], off, 64);
  }
  if (lane == 0) {
#pragma unroll
    for (int c = 0; c < N; ++c) red[wv * N + c] = v[c];
  }
  __syncthreads();
#pragma unroll
  for (int c = 0; c < N; ++c) {
    float s = 0.f;
#pragma unroll
    for (int w = 0; w < NWAVE; ++w) s += red[w * N + c];
    v[c] = s;
  }
  __syncthreads();  // protect scratch for next reduce
}

// LayerNorm (population var) + affine + ReLU over the block's 384 values.
__device__ __forceinline__ float ln_relu(float xv, float g_i, float b_i,
                                         float* red, int tid) {
  float v[2] = {xv, xv * xv};
  block_reduce<2>(v, red, tid);
  const float inv = 1.0f / (float)DHv;
  float m   = v[0] * inv;
  float var = v[1] * inv - m * m;
  float y = (xv - m) * rsqrtf(var + 1e-5f) * g_i + b_i;
  return fmaxf(y, 0.0f);
}

__global__ __launch_bounds__(384) void fw_rnn_kernel(
    const float* __restrict__ z_seq,   // [T, B, DG]
    const float* __restrict__ W_h,     // [DH, DH]
    const float* __restrict__ W_g,     // [DH, DG]
    const float* __restrict__ b_h,     // [DH]
    const float* __restrict__ ln_g,    // [DH]
    const float* __restrict__ ln_b,    // [DH]
    const float* __restrict__ alpha_fw,// [1]
    float* __restrict__ out)           // [B, DH]
{
  __shared__ float hist[NSTEP * DHv];  // h_0..h_46 for this batch element
  __shared__ float hs[DHv];            // current settling state
  __shared__ float zsh[DGv];           // staged z_t
  __shared__ float wlam[NSTEP];        // eta * lam^(t-1-tau) coefficients
  __shared__ float carr[NSTEP];        // per-tau weighted dots
  __shared__ float red[NWAVE * 3];     // reduction scratch

  const int tid  = threadIdx.x;
  const int b    = blockIdx.x;
  const int lane = tid & 63, wv = tid >> 6;

  const float bh_i = b_h[tid];
  const float g_i  = ln_g[tid];
  const float be_i = ln_b[tid];

  // k = curvature of cosine gate (scalar, computed redundantly per thread)
  const float af = alpha_fw[0];
  const float k  = (af >= 0.f) ? (1.f + log1pf(expf(af)))
                               : (1.f / (1.f + log1pf(expf(-af))));

  for (int t = 0; t < NSTEP; ++t) {
    // ---- stage z_t into LDS ----
    if (tid < DGv / 4) {
      ((float4*)zsh)[tid] =
          ((const float4*)(z_seq + ((size_t)t * BB + b) * DGv))[tid];
    }
    __syncthreads();

    // ---- h_base = W_h h_prev + W_g z_t + b_h (thread i -> row i) ----
    float hb = bh_i;
    {
      const float4* wg4 = (const float4*)(W_g + (size_t)tid * DGv);
      const float4* z4  = (const float4*)zsh;
#pragma unroll 8
      for (int j = 0; j < DGv / 4; ++j) {
        float4 w = wg4[j], z = z4[j];
        hb = fmaf(w.x, z.x, hb); hb = fmaf(w.y, z.y, hb);
        hb = fmaf(w.z, z.z, hb); hb = fmaf(w.w, z.w, hb);
      }
    }
    if (t > 0) {
      const float4* wh4 = (const float4*)(W_h + (size_t)tid * DHv);
      const float4* hp4 = (const float4*)(hist + (size_t)(t - 1) * DHv);
#pragma unroll 8
      for (int j = 0; j < DHv / 4; ++j) {
        float4 w = wh4[j], h = hp4[j];
        hb = fmaf(w.x, h.x, hb); hb = fmaf(w.y, h.y, hb);
        hb = fmaf(w.z, h.z, hb); hb = fmaf(w.w, h.w, hb);
      }
    }

    // ---- h_s = relu(LN(h_base)) ----
    float hsv = ln_relu(hb, g_i, be_i, red, tid);
    hs[tid] = hsv;
    __syncthreads();

    // ---- settling loop ----
    for (int s = 0; s < SETI; ++s) {
      // c_tau = w_tau * (h_tau . h_s) ; waves split tau-space
      for (int tau = wv; tau < t; tau += NWAVE) {
        const float* hr = hist + (size_t)tau * DHv;
        float p = 0.f;
#pragma unroll
        for (int r = 0; r < NWAVE; ++r)
          p = fmaf(hr[lane + 64 * r], hs[lane + 64 * r], p);
        p = wave_reduce(p);
        if (lane == 0) carr[tau] = p * wlam[tau];
      }
      __syncthreads();

      // Ah[i] = sum_tau c_tau * h_tau[i]
      float ah = 0.f;
      for (int tau = 0; tau < t; ++tau)
        ah = fmaf(carr[tau], hist[(size_t)tau * DHv + tid], ah);

      // cosine gate (per-row scalars)
      float v3[3] = {hsv * ah, hsv * hsv, ah * ah};
      block_reduce<3>(v3, red, tid);
      float n1 = fmaxf(sqrtf(v3[1]), 1e-6f);
      float n2 = fmaxf(sqrtf(v3[2]), 1e-6f);
      float R  = v3[0] / (n1 * n2);
      R = fminf(fmaxf(R, 0.f), 1.f);
      float a = 1.f - powf(1.f - R, k);

      float xv = (1.f - a * a) * hb + a * ah;
      hsv = ln_relu(xv, g_i, be_i, red, tid);
      hs[tid] = hsv;
      __syncthreads();
    }

    // ---- commit h_t to history; update decay weights ----
    hist[(size_t)t * DHv + tid] = hsv;
    if (tid < t) wlam[tid] *= 0.9f;   // existing taus decay
    if (tid == t) wlam[tid] = 0.5f;   // eta for the new entry
    __syncthreads();
  }

  // ================= final (query) step, t = T-1 =================
  {
    const int t = NSTEP;  // 47
    if (tid < DGv / 4) {
      ((float4*)zsh)[tid] =
          ((const float4*)(z_seq + ((size_t)t * BB + b) * DGv))[tid];
    }
    __syncthreads();

    float hb = bh_i;
    {
      const float4* wg4 = (const float4*)(W_g + (size_t)tid * DGv);
      const float4* z4  = (const float4*)zsh;
#pragma unroll 8
      for (int j = 0; j < DGv / 4; ++j) {
        float4 w = wg4[j], z = z4[j];
        hb = fmaf(w.x, z.x, hb); hb = fmaf(w.y, z.y, hb);
        hb = fmaf(w.z, z.z, hb); hb = fmaf(w.w, z.w, hb);
      }
    }
    {
      const float4* wh4 = (const float4*)(W_h + (size_t)tid * DHv);
      const float4* hp4 = (const float4*)(hist + (size_t)(NSTEP - 1) * DHv);
#pragma unroll 8
      for (int j = 0; j < DHv / 4; ++j) {
        float4 w = wh4[j], h = hp4[j];
        hb = fmaf(w.x, h.x, hb); hb = fmaf(w.y, h.y, hb);
        hb = fmaf(w.z, h.z, hb); hb = fmaf(w.w, h.w, hb);
      }
    }

    float hv = ln_relu(hb, g_i, be_i, red, tid);
    hs[tid] = hv;
    __syncthreads();

    // h = relu(LN(h_base + A h)) x3 ; wlam now holds eta*lam^(46-tau)
    for (int s = 0; s < SETI; ++s) {
      for (int tau = wv; tau < NSTEP; tau += NWAVE) {
        const float* hr = hist + (size_t)tau * DHv;
        float p = 0.f;
#pragma unroll
        for (int r = 0; r < NWAVE; ++r)
          p = fmaf(hr[lane + 64 * r], hs[lane + 64 * r], p);
        p = wave_reduce(p);
        if (lane == 0) carr[tau] = p * wlam[tau];
      }
      __syncthreads();

      float ah = 0.f;
      for (int tau = 0; tau < NSTEP; ++tau)
        ah = fmaf(carr[tau], hist[(size_t)tau * DHv + tid], ah);

      hv = ln_relu(hb + ah, g_i, be_i, red, tid);
      hs[tid] = hv;
      __syncthreads();
    }

    out[(size_t)b * DHv + tid] = hv;
  }
}

extern "C" void kernel_launch(void* const* d_in, const int* in_sizes, int n_in,
                              void* d_out, int out_size, void* d_ws, size_t ws_size,
                              hipStream_t stream) {
  const float* z_seq    = (const float*)d_in[0];
  const float* W_h      = (const float*)d_in[1];
  const float* W_g      = (const float*)d_in[2];
  const float* b_h      = (const float*)d_in[3];
  const float* ln_g     = (const float*)d_in[4];
  const float* ln_b     = (const float*)d_in[5];
  const float* alpha_fw = (const float*)d_in[6];
  float* out = (float*)d_out;

  fw_rnn_kernel<<<dim3(BB), dim3(DHv), 0, stream>>>(
      z_seq, W_h, W_g, b_h, ln_g, ln_b, alpha_fw, out);
}

// Round 2
// 943.170 us; speedup vs baseline: 1.8571x; 1.8571x over previous
//
#include <hip/hip_runtime.h>
#include <math.h>

// Problem constants
#define TT    48
#define BB    96
#define DG    192
#define DH    384
#define NSTEP 47     // T-1 scan steps
#define SETI  3      // inner settling iterations
#define NT    768    // threads per block
#define NWAVE 12     // 768/64
#define NG    48     // 16-lane groups per block

__device__ __forceinline__ float group16_reduce(float v) {
  v += __shfl_xor(v, 8, 64);
  v += __shfl_xor(v, 4, 64);
  v += __shfl_xor(v, 2, 64);
  v += __shfl_xor(v, 1, 64);
  return v;
}

// Block-wide sum of N values across 768 threads (12 waves).
// All threads return identical sums. 2 barriers.
template <int N>
__device__ __forceinline__ void block_reduce(float (&v)[N], float* red, int tid) {
  const int lane = tid & 63, wv = tid >> 6;
#pragma unroll
  for (int c = 0; c < N; ++c) {
#pragma unroll
    for (int off = 32; off; off >>= 1) v[c] += __shfl_xor(v[c], off, 64);
  }
  if (lane == 0) {
#pragma unroll
    for (int c = 0; c < N; ++c) red[wv * N + c] = v[c];
  }
  __syncthreads();
#pragma unroll
  for (int c = 0; c < N; ++c) {
    float s = 0.f;
#pragma unroll
    for (int w = 0; w < NWAVE; ++w) s += red[w * N + c];
    v[c] = s;
  }
  __syncthreads();
}

// LayerNorm + affine + ReLU over the 384 owner values (tid<DH); non-owners
// must pass xv=0. All 768 threads participate (barriers).
__device__ __forceinline__ float ln_relu(float xv, float g_i, float b_i,
                                         float* red, int tid) {
  float v[2] = {xv, xv * xv};
  block_reduce<2>(v, red, tid);
  const float inv = 1.0f / (float)DH;
  float m   = v[0] * inv;
  float var = v[1] * inv - m * m;
  float y = (xv - m) * rsqrtf(var + 1e-5f) * g_i + b_i;
  return fmaxf(y, 0.0f);
}

// hbs[r] = W_g[r,:].z + (with_h ? W_h[r,:].hprev : 0) + b[r], r = 0..383.
// Coalesced: 16-lane group g handles row r = p*48+g; 16 lanes read 256 B
// contiguous per float4 instruction.
__device__ __forceinline__ void matvec(const float* __restrict__ W_g,
                                       const float* __restrict__ W_h,
                                       const float* hprev, const float* zsh,
                                       const float* bhs, float* hbs,
                                       int g, int lane16, bool with_h) {
  const float4* z4 = (const float4*)zsh;
  const float4* h4 = (const float4*)hprev;
#pragma unroll 2
  for (int p = 0; p < 8; ++p) {
    const int r = p * NG + g;
    float acc = 0.f;
    const float4* wg = (const float4*)(W_g) + (size_t)r * (DG / 4);
#pragma unroll
    for (int k = 0; k < 3; ++k) {
      float4 w = wg[lane16 + 16 * k], z = z4[lane16 + 16 * k];
      acc = fmaf(w.x, z.x, acc); acc = fmaf(w.y, z.y, acc);
      acc = fmaf(w.z, z.z, acc); acc = fmaf(w.w, z.w, acc);
    }
    if (with_h) {
      const float4* wh = (const float4*)(W_h) + (size_t)r * (DH / 4);
#pragma unroll
      for (int k = 0; k < 6; ++k) {
        float4 w = wh[lane16 + 16 * k], h = h4[lane16 + 16 * k];
        acc = fmaf(w.x, h.x, acc); acc = fmaf(w.y, h.y, acc);
        acc = fmaf(w.z, h.z, acc); acc = fmaf(w.w, h.w, acc);
      }
    }
    acc = group16_reduce(acc);
    if (lane16 == 0) hbs[r] = acc + bhs[r];
  }
}

__global__ __launch_bounds__(NT) void fw_rnn_kernel(
    const float* __restrict__ z_seq,    // [T, B, DG]
    const float* __restrict__ W_h,      // [DH, DH]
    const float* __restrict__ W_g,      // [DH, DG]
    const float* __restrict__ b_h,      // [DH]
    const float* __restrict__ ln_g,     // [DH]
    const float* __restrict__ ln_b,     // [DH]
    const float* __restrict__ alpha_fw, // [1]
    float* __restrict__ out)            // [B, DH]
{
  __shared__ float hist[NSTEP * DH];   // h_0..h_46
  __shared__ float hs[DH];             // current settling state
  __shared__ float zsh[DG];            // staged z_t
  __shared__ float hbs[DH];            // h_base for this step
  __shared__ float bhs[DH];            // staged bias
  __shared__ float wlam[NSTEP];        // eta * lam^(t-1-tau)
  __shared__ float carr[NG];           // per-tau weighted dots
  __shared__ float red[NWAVE * 3];     // reduction scratch

  const int tid    = threadIdx.x;
  const int b      = blockIdx.x;
  const int g      = tid >> 4;         // 16-lane group id, 0..47
  const int lane16 = tid & 15;
  const bool owner = (tid < DH);

  float g_i = 0.f, be_i = 0.f;
  if (owner) {
    bhs[tid] = b_h[tid];
    g_i  = ln_g[tid];
    be_i = ln_b[tid];
  }

  const float af = alpha_fw[0];
  const float k  = (af >= 0.f) ? (1.f + log1pf(expf(af)))
                               : (1.f / (1.f + log1pf(expf(-af))));
  __syncthreads();

  for (int t = 0; t < NSTEP; ++t) {
    // ---- stage z_t ----
    if (tid < DG / 4) {
      ((float4*)zsh)[tid] =
          ((const float4*)(z_seq + ((size_t)t * BB + b) * DG))[tid];
    }
    __syncthreads();  // z visible; prev hist commit visible

    // ---- h_base ----
    matvec(W_g, W_h, hist + (size_t)(t - 1) * DH, zsh, bhs, hbs, g, lane16,
           t > 0);
    __syncthreads();

    float hb = owner ? hbs[tid] : 0.f;
    float hsv = ln_relu(owner ? hb : 0.f, g_i, be_i, red, tid);
    if (owner) hs[tid] = hsv;
    __syncthreads();

    // ---- settling (identity at t==0 since A==0) ----
    if (t > 0) {
      for (int s = 0; s < SETI; ++s) {
        // d_tau = w_tau * (h_tau . h_s): one 16-lane group per tau
        if (g < t) {
          const float4* h4 = (const float4*)(hist + (size_t)g * DH);
          const float4* s4 = (const float4*)hs;
          float p = 0.f;
#pragma unroll
          for (int kk = 0; kk < 6; ++kk) {
            float4 hh = h4[lane16 + 16 * kk], ss = s4[lane16 + 16 * kk];
            p = fmaf(hh.x, ss.x, p); p = fmaf(hh.y, ss.y, p);
            p = fmaf(hh.z, ss.z, p); p = fmaf(hh.w, ss.w, p);
          }
          p = group16_reduce(p);
          if (lane16 == 0) carr[g] = p * wlam[g];
        }
        __syncthreads();

        // Ah[i] = sum_tau c_tau h_tau[i]
        float ah = 0.f;
        if (owner) {
          for (int tau = 0; tau < t; ++tau)
            ah = fmaf(carr[tau], hist[(size_t)tau * DH + tid], ah);
        }

        // cosine gate
        float v3[3];
        v3[0] = owner ? hsv * ah : 0.f;
        v3[1] = owner ? hsv * hsv : 0.f;
        v3[2] = owner ? ah * ah : 0.f;
        block_reduce<3>(v3, red, tid);
        float n1 = fmaxf(sqrtf(v3[1]), 1e-6f);
        float n2 = fmaxf(sqrtf(v3[2]), 1e-6f);
        float R  = fminf(fmaxf(v3[0] / (n1 * n2), 0.f), 1.f);
        float a  = 1.f - powf(1.f - R, k);

        float xv = owner ? (1.f - a * a) * hb + a * ah : 0.f;
        hsv = ln_relu(xv, g_i, be_i, red, tid);
        if (owner) hs[tid] = hsv;
        __syncthreads();
      }
    }

    // ---- commit h_t; update decay weights ----
    if (owner) hist[(size_t)t * DH + tid] = hsv;
    if (tid < t) wlam[tid] *= 0.9f;
    if (tid == t) wlam[tid] = 0.5f;
    __syncthreads();
  }

  // ================= final (query) step =================
  {
    if (tid < DG / 4) {
      ((float4*)zsh)[tid] =
          ((const float4*)(z_seq + ((size_t)NSTEP * BB + b) * DG))[tid];
    }
    __syncthreads();

    matvec(W_g, W_h, hist + (size_t)(NSTEP - 1) * DH, zsh, bhs, hbs, g, lane16,
           true);
    __syncthreads();

    float hb = owner ? hbs[tid] : 0.f;
    float hv = ln_relu(owner ? hb : 0.f, g_i, be_i, red, tid);
    if (owner) hs[tid] = hv;
    __syncthreads();

    for (int s = 0; s < SETI; ++s) {
      if (g < NSTEP) {
        const float4* h4 = (const float4*)(hist + (size_t)g * DH);
        const float4* s4 = (const float4*)hs;
        float p = 0.f;
#pragma unroll
        for (int kk = 0; kk < 6; ++kk) {
          float4 hh = h4[lane16 + 16 * kk], ss = s4[lane16 + 16 * kk];
          p = fmaf(hh.x, ss.x, p); p = fmaf(hh.y, ss.y, p);
          p = fmaf(hh.z, ss.z, p); p = fmaf(hh.w, ss.w, p);
        }
        p = group16_reduce(p);
        if (lane16 == 0) carr[g] = p * wlam[g];
      }
      __syncthreads();

      float ah = 0.f;
      if (owner) {
        for (int tau = 0; tau < NSTEP; ++tau)
          ah = fmaf(carr[tau], hist[(size_t)tau * DH + tid], ah);
      }

      hv = ln_relu(owner ? hb + ah : 0.f, g_i, be_i, red, tid);
      if (owner) hs[tid] = hv;
      __syncthreads();
    }

    if (owner) out[(size_t)b * DH + tid] = hv;
  }
}

extern "C" void kernel_launch(void* const* d_in, const int* in_sizes, int n_in,
                              void* d_out, int out_size, void* d_ws, size_t ws_size,
                              hipStream_t stream) {
  const float* z_seq    = (const float*)d_in[0];
  const float* W_h      = (const float*)d_in[1];
  const float* W_g      = (const float*)d_in[2];
  const float* b_h      = (const float*)d_in[3];
  const float* ln_g     = (const float*)d_in[4];
  const float* ln_b     = (const float*)d_in[5];
  const float* alpha_fw = (const float*)d_in[6];
  float* out = (float*)d_out;

  fw_rnn_kernel<<<dim3(BB), dim3(NT), 0, stream>>>(
      z_seq, W_h, W_g, b_h, ln_g, ln_b, alpha_fw, out);
}

// Round 3
// 803.041 us; speedup vs baseline: 2.1812x; 1.1745x over previous
//
#include <hip/hip_runtime.h>
#include <math.h>

// Problem constants
#define TT    48
#define BB    96
#define DG    192
#define DH    384
#define NSTEP 47     // T-1 scan steps
#define SETI  3      // inner settling iterations
#define NT    768    // threads per block
#define NWAVE 12     // 768/64
#define NOW   6      // owner waves (tid < DH)
#define NG    48     // 16-lane groups per block

typedef unsigned short ushort_t;

__device__ __forceinline__ float group16_reduce(float v) {
  v += __shfl_xor(v, 8, 64);
  v += __shfl_xor(v, 4, 64);
  v += __shfl_xor(v, 2, 64);
  v += __shfl_xor(v, 1, 64);
  return v;
}

__device__ __forceinline__ float blo(unsigned u) {
  return __uint_as_float(u << 16);
}
__device__ __forceinline__ float bhi(unsigned u) {
  return __uint_as_float(u & 0xFFFF0000u);
}

// matvec: hbs[r] = W_g[r,:].z + (with_h ? W_h[r,:].hprev : 0) + bias.
// 16-lane group g handles rows r = p*48+g. Also accumulates per-thread
// partial LN stats (s1 += hb, s2 += hb^2) on lane16==0 threads.
template <bool BF16W>
__device__ __forceinline__ void matvec(
    const float* __restrict__ Wh_f, const float* __restrict__ Wg_f,
    const ushort_t* __restrict__ Wh_b, const ushort_t* __restrict__ Wg_b,
    const float* __restrict__ hprev, const float* __restrict__ zsh,
    const float (&bias)[8], float* __restrict__ hbs,
    float& s1, float& s2, int g, int lane16, bool with_h)
{
  const float4* z4 = (const float4*)zsh;
  const float4* h4 = (const float4*)hprev;
#pragma unroll 2
  for (int p = 0; p < 8; ++p) {
    const int r = p * NG + g;
    float acc = 0.f;
    if (BF16W) {
      const uint2* wg = (const uint2*)Wg_b + (size_t)r * (DG / 4);
#pragma unroll
      for (int c = 0; c < 3; ++c) {
        uint2 u = wg[lane16 + 16 * c];
        float4 z = z4[lane16 + 16 * c];
        acc = fmaf(blo(u.x), z.x, acc); acc = fmaf(bhi(u.x), z.y, acc);
        acc = fmaf(blo(u.y), z.z, acc); acc = fmaf(bhi(u.y), z.w, acc);
      }
      if (with_h) {
        const uint4* wh = (const uint4*)Wh_b + (size_t)r * (DH / 8);
#pragma unroll
        for (int c = 0; c < 3; ++c) {
          uint4 u = wh[lane16 + 16 * c];
          float4 ha = h4[(lane16 + 16 * c) * 2];
          float4 hb2 = h4[(lane16 + 16 * c) * 2 + 1];
          acc = fmaf(blo(u.x), ha.x, acc);  acc = fmaf(bhi(u.x), ha.y, acc);
          acc = fmaf(blo(u.y), ha.z, acc);  acc = fmaf(bhi(u.y), ha.w, acc);
          acc = fmaf(blo(u.z), hb2.x, acc); acc = fmaf(bhi(u.z), hb2.y, acc);
          acc = fmaf(blo(u.w), hb2.z, acc); acc = fmaf(bhi(u.w), hb2.w, acc);
        }
      }
    } else {
      const float4* wg = (const float4*)Wg_f + (size_t)r * (DG / 4);
#pragma unroll
      for (int c = 0; c < 3; ++c) {
        float4 w = wg[lane16 + 16 * c], z = z4[lane16 + 16 * c];
        acc = fmaf(w.x, z.x, acc); acc = fmaf(w.y, z.y, acc);
        acc = fmaf(w.z, z.z, acc); acc = fmaf(w.w, z.w, acc);
      }
      if (with_h) {
        const float4* wh = (const float4*)Wh_f + (size_t)r * (DH / 4);
#pragma unroll
        for (int c = 0; c < 6; ++c) {
          float4 w = wh[lane16 + 16 * c], h = h4[lane16 + 16 * c];
          acc = fmaf(w.x, h.x, acc); acc = fmaf(w.y, h.y, acc);
          acc = fmaf(w.z, h.z, acc); acc = fmaf(w.w, h.w, acc);
        }
      }
    }
    acc = group16_reduce(acc);
    if (lane16 == 0) {
      float vv = acc + bias[p];
      hbs[r] = vv;
      s1 += vv;
      s2 += vv * vv;
    }
  }
}

template <bool BF16W>
__global__ __launch_bounds__(NT) void fw_rnn_kernel(
    const float* __restrict__ z_seq,    // [T, B, DG]
    const float* __restrict__ Wh_f,     // [DH, DH] fp32
    const float* __restrict__ Wg_f,     // [DH, DG] fp32
    const ushort_t* __restrict__ Wh_b,  // bf16 copies (in ws)
    const ushort_t* __restrict__ Wg_b,
    const float* __restrict__ b_h,
    const float* __restrict__ ln_g,
    const float* __restrict__ ln_b,
    const float* __restrict__ alpha_fw,
    float* __restrict__ out)            // [B, DH]
{
  __shared__ float hist[NSTEP * DH];
  __shared__ float hs[DH];
  __shared__ float zsh[DG];
  __shared__ float hbs[DH];
  __shared__ float wlam[NSTEP];
  __shared__ float carr[NG];
  __shared__ float redA[NWAVE * 2];
  __shared__ float redB[2][NOW * 5];

  const int tid    = threadIdx.x;
  const int b      = blockIdx.x;
  const int lane   = tid & 63, wv = tid >> 6;
  const int g      = tid >> 4, lane16 = tid & 15;
  const bool owner = (tid < DH);

  float bias[8];
#pragma unroll
  for (int p = 0; p < 8; ++p) bias[p] = 0.f;
  if (lane16 == 0) {
#pragma unroll
    for (int p = 0; p < 8; ++p) bias[p] = b_h[p * NG + g];
  }
  float g_i = 0.f, be_i = 0.f;
  if (owner) { g_i = ln_g[tid]; be_i = ln_b[tid]; }

  const float af   = alpha_fw[0];
  const float kcur = (af >= 0.f) ? (1.f + log1pf(expf(af)))
                                 : (1.f / (1.f + log1pf(expf(-af))));
  const float invD = 1.0f / (float)DH;

  // stage z_0
  if (tid < DG / 4)
    ((float4*)zsh)[tid] = ((const float4*)(z_seq + (size_t)b * DG))[tid];
  __syncthreads();

  float Shb = 0.f, Shb2 = 0.f;

  for (int t = 0; t < NSTEP; ++t) {
    // ---------- base phase: h_base + fused LN stats ----------
    float s1 = 0.f, s2 = 0.f;
    matvec<BF16W>(Wh_f, Wg_f, Wh_b, Wg_b,
                  hist + (size_t)(t > 0 ? t - 1 : 0) * DH, zsh, bias, hbs,
                  s1, s2, g, lane16, t > 0);
    {
      float v0 = s1, v1 = s2;
#pragma unroll
      for (int off = 32; off; off >>= 1) {
        v0 += __shfl_xor(v0, off, 64);
        v1 += __shfl_xor(v1, off, 64);
      }
      if (lane == 0) { redA[wv * 2] = v0; redA[wv * 2 + 1] = v1; }
    }
    __syncthreads();  // (a): hbs + redA visible

    float hb = 0.f, hsv = 0.f;
    {
      float S1 = 0.f, S2 = 0.f;
#pragma unroll
      for (int w = 0; w < NWAVE; ++w) { S1 += redA[w * 2]; S2 += redA[w * 2 + 1]; }
      Shb = S1; Shb2 = S2;
      if (owner) {
        hb = hbs[tid];
        float m   = S1 * invD;
        float var = S2 * invD - m * m;
        hsv = fmaxf((hb - m) * rsqrtf(var + 1e-5f) * g_i + be_i, 0.f);
        hs[tid] = hsv;
      }
    }
    if (t == 0) {
      // A == 0: settling is identity. Commit, init wlam, stage z_1.
      if (owner) hist[tid] = hsv;
      if (tid == 0) wlam[0] = 0.5f;
      if (tid >= DH && tid < DH + DG / 4)
        ((float4*)zsh)[tid - DH] =
            ((const float4*)(z_seq + ((size_t)1 * BB + b) * DG))[tid - DH];
      __syncthreads();  // (b)
      continue;
    }
    __syncthreads();  // (b): hs visible

    // ---------- settling iterations ----------
    for (int s = 0; s < SETI; ++s) {
      // phase A: d_tau = wlam_tau * (h_tau . h_s), one 16-lane group per tau
      if (g < t) {
        const float4* h4 = (const float4*)(hist + (size_t)g * DH);
        const float4* s4 = (const float4*)hs;
        float p = 0.f;
#pragma unroll
        for (int kk = 0; kk < 6; ++kk) {
          float4 hh = h4[lane16 + 16 * kk], ss = s4[lane16 + 16 * kk];
          p = fmaf(hh.x, ss.x, p); p = fmaf(hh.y, ss.y, p);
          p = fmaf(hh.z, ss.z, p); p = fmaf(hh.w, ss.w, p);
        }
        p = group16_reduce(p);
        if (lane16 == 0) carr[g] = p * wlam[g];
      }
      __syncthreads();  // (i): carr visible

      // phase B: owners compute Ah + 5 partial sums
      float ah = 0.f;
      if (owner) {
        for (int tau = 0; tau < t; ++tau)
          ah = fmaf(carr[tau], hist[(size_t)tau * DH + tid], ah);
        float v0 = hsv * ah, v1 = hsv * hsv, v2 = ah * ah, v3 = hb * ah, v4 = ah;
#pragma unroll
        for (int off = 32; off; off >>= 1) {
          v0 += __shfl_xor(v0, off, 64);
          v1 += __shfl_xor(v1, off, 64);
          v2 += __shfl_xor(v2, off, 64);
          v3 += __shfl_xor(v3, off, 64);
          v4 += __shfl_xor(v4, off, 64);
        }
        if (lane == 0) {
          float* rb = redB[s & 1];
          rb[wv * 5 + 0] = v0; rb[wv * 5 + 1] = v1; rb[wv * 5 + 2] = v2;
          rb[wv * 5 + 3] = v3; rb[wv * 5 + 4] = v4;
        }
      }
      __syncthreads();  // (ii): redB visible

      // phase C: gate + analytic LN + commit
      if (owner) {
        const float* rb = redB[s & 1];
        float S0 = 0, S1 = 0, S2 = 0, S3 = 0, S4 = 0;
#pragma unroll
        for (int w = 0; w < NOW; ++w) {
          S0 += rb[w * 5 + 0]; S1 += rb[w * 5 + 1]; S2 += rb[w * 5 + 2];
          S3 += rb[w * 5 + 3]; S4 += rb[w * 5 + 4];
        }
        float n1 = fmaxf(sqrtf(S1), 1e-6f);
        float n2 = fmaxf(sqrtf(S2), 1e-6f);
        float R  = fminf(fmaxf(S0 / (n1 * n2), 0.f), 1.f);
        float a  = 1.f - powf(1.f - R, kcur);
        float beta = 1.f - a * a;
        float mu  = (beta * Shb + a * S4) * invD;
        float Exx = (beta * beta * Shb2 + 2.f * beta * a * S3 + a * a * S2) * invD;
        float var = Exx - mu * mu;
        float xv  = beta * hb + a * ah;
        hsv = fmaxf((xv - mu) * rsqrtf(var + 1e-5f) * g_i + be_i, 0.f);
        hs[tid] = hsv;
        if (s == SETI - 1) hist[(size_t)t * DH + tid] = hsv;
      }
      if (s == SETI - 1) {
        if (tid < t) wlam[tid] *= 0.9f;
        else if (tid == t) wlam[tid] = 0.5f;
        if (tid >= DH && tid < DH + DG / 4)
          ((float4*)zsh)[tid - DH] =
              ((const float4*)(z_seq + ((size_t)(t + 1) * BB + b) * DG))[tid - DH];
      }
      __syncthreads();  // (iii)
    }
  }

  // ================= final (query) step =================
  {
    float s1 = 0.f, s2 = 0.f;
    matvec<BF16W>(Wh_f, Wg_f, Wh_b, Wg_b,
                  hist + (size_t)(NSTEP - 1) * DH, zsh, bias, hbs,
                  s1, s2, g, lane16, true);
    {
      float v0 = s1, v1 = s2;
#pragma unroll
      for (int off = 32; off; off >>= 1) {
        v0 += __shfl_xor(v0, off, 64);
        v1 += __shfl_xor(v1, off, 64);
      }
      if (lane == 0) { redA[wv * 2] = v0; redA[wv * 2 + 1] = v1; }
    }
    __syncthreads();

    float hb = 0.f, hv = 0.f;
    {
      float S1 = 0.f, S2 = 0.f;
#pragma unroll
      for (int w = 0; w < NWAVE; ++w) { S1 += redA[w * 2]; S2 += redA[w * 2 + 1]; }
      Shb = S1; Shb2 = S2;
      if (owner) {
        hb = hbs[tid];
        float m   = S1 * invD;
        float var = S2 * invD - m * m;
        hv = fmaxf((hb - m) * rsqrtf(var + 1e-5f) * g_i + be_i, 0.f);
        hs[tid] = hv;
      }
    }
    __syncthreads();

    for (int s = 0; s < SETI; ++s) {
      if (g < NSTEP) {
        const float4* h4 = (const float4*)(hist + (size_t)g * DH);
        const float4* s4 = (const float4*)hs;
        float p = 0.f;
#pragma unroll
        for (int kk = 0; kk < 6; ++kk) {
          float4 hh = h4[lane16 + 16 * kk], ss = s4[lane16 + 16 * kk];
          p = fmaf(hh.x, ss.x, p); p = fmaf(hh.y, ss.y, p);
          p = fmaf(hh.z, ss.z, p); p = fmaf(hh.w, ss.w, p);
        }
        p = group16_reduce(p);
        if (lane16 == 0) carr[g] = p * wlam[g];
      }
      __syncthreads();

      float ah = 0.f;
      if (owner) {
        for (int tau = 0; tau < NSTEP; ++tau)
          ah = fmaf(carr[tau], hist[(size_t)tau * DH + tid], ah);
        float v0 = ah, v1 = ah * ah, v2 = hb * ah;
#pragma unroll
        for (int off = 32; off; off >>= 1) {
          v0 += __shfl_xor(v0, off, 64);
          v1 += __shfl_xor(v1, off, 64);
          v2 += __shfl_xor(v2, off, 64);
        }
        if (lane == 0) {
          float* rb = redB[s & 1];
          rb[wv * 5 + 0] = v0; rb[wv * 5 + 1] = v1; rb[wv * 5 + 2] = v2;
        }
      }
      __syncthreads();

      if (owner) {
        const float* rb = redB[s & 1];
        float S0 = 0, S1 = 0, S2 = 0;
#pragma unroll
        for (int w = 0; w < NOW; ++w) {
          S0 += rb[w * 5 + 0]; S1 += rb[w * 5 + 1]; S2 += rb[w * 5 + 2];
        }
        // xv = hb + ah : analytic stats
        float Sx  = Shb + S0;
        float Sxx = Shb2 + 2.f * S2 + S1;
        float mu  = Sx * invD;
        float var = Sxx * invD - mu * mu;
        float xv  = hb + ah;
        hv = fmaxf((xv - mu) * rsqrtf(var + 1e-5f) * g_i + be_i, 0.f);
        if (s < SETI - 1) hs[tid] = hv;
      }
      if (s < SETI - 1) __syncthreads();
    }

    if (owner) out[(size_t)b * DH + tid] = hv;
  }
}

// fp32 -> bf16 (RTN-even) conversion for W matrices
__global__ void cvt_kernel(const float* __restrict__ src,
                           ushort_t* __restrict__ dst, int n) {
  int i = blockIdx.x * blockDim.x + threadIdx.x;
  if (i < n) {
    unsigned u = __float_as_uint(src[i]);
    unsigned r = (u + 0x7FFFu + ((u >> 16) & 1u)) >> 16;
    dst[i] = (ushort_t)r;
  }
}

extern "C" void kernel_launch(void* const* d_in, const int* in_sizes, int n_in,
                              void* d_out, int out_size, void* d_ws, size_t ws_size,
                              hipStream_t stream) {
  const float* z_seq    = (const float*)d_in[0];
  const float* W_h      = (const float*)d_in[1];
  const float* W_g      = (const float*)d_in[2];
  const float* b_h      = (const float*)d_in[3];
  const float* ln_g     = (const float*)d_in[4];
  const float* ln_b     = (const float*)d_in[5];
  const float* alpha_fw = (const float*)d_in[6];
  float* out = (float*)d_out;

  const size_t nWh = (size_t)DH * DH;  // 147456
  const size_t nWg = (size_t)DH * DG;  // 73728

  if (ws_size >= (nWh + nWg) * sizeof(ushort_t)) {
    ushort_t* Whb = (ushort_t*)d_ws;
    ushort_t* Wgb = Whb + nWh;
    cvt_kernel<<<dim3((int)((nWh + 255) / 256)), dim3(256), 0, stream>>>(
        W_h, Whb, (int)nWh);
    cvt_kernel<<<dim3((int)((nWg + 255) / 256)), dim3(256), 0, stream>>>(
        W_g, Wgb, (int)nWg);
    fw_rnn_kernel<true><<<dim3(BB), dim3(NT), 0, stream>>>(
        z_seq, W_h, W_g, Whb, Wgb, b_h, ln_g, ln_b, alpha_fw, out);
  } else {
    fw_rnn_kernel<false><<<dim3(BB), dim3(NT), 0, stream>>>(
        z_seq, W_h, W_g, nullptr, nullptr, b_h, ln_g, ln_b, alpha_fw, out);
  }
}